// Round 1
// baseline (1056.056 us; speedup 1.0000x reference)
//
#include <hip/hip_runtime.h>

#define H 256
#define Bg 1024
#define EPSV 1e-5f

__device__ __forceinline__ int lower_bound_dev(const int* __restrict__ a, int n, int key) {
    int lo = 0, hi = n;
    while (lo < hi) {
        int mid = (lo + hi) >> 1;
        if (a[mid] < key) lo = mid + 1; else hi = mid;
    }
    return lo;
}

// K1: one block per graph. Binary-search segment bounds in sorted batch_idx,
// float4-coalesced column sums, + virtual_node -> h0. Block 0 zeroes BN stat accum.
__global__ void __launch_bounds__(256) seg_sum_k(const float* __restrict__ x,
                                                 const int* __restrict__ bidx,
                                                 const float* __restrict__ vnode,
                                                 float* __restrict__ h0,
                                                 float* __restrict__ colsum,
                                                 float* __restrict__ colsumsq,
                                                 int N) {
    const int b = blockIdx.x;
    const int t = threadIdx.x;
    if (b == 0) { colsum[t] = 0.0f; colsumsq[t] = 0.0f; }

    const int start = lower_bound_dev(bidx, N, b);
    const int end   = lower_bound_dev(bidx, N, b + 1);

    const int sub = t >> 6;          // 0..3 : row phase
    const int c4  = (t & 63) << 2;   // column group (float4)

    float4 acc = make_float4(0.f, 0.f, 0.f, 0.f);
    for (int r = start + sub; r < end; r += 4) {
        const float4 v = *reinterpret_cast<const float4*>(x + (size_t)r * H + c4);
        acc.x += v.x; acc.y += v.y; acc.z += v.z; acc.w += v.w;
    }

    __shared__ float4 red[256];
    red[t] = acc;
    __syncthreads();
    if (sub == 0) {
        float4 s0 = red[t];
        const float4 s1 = red[t + 64];
        const float4 s2 = red[t + 128];
        const float4 s3 = red[t + 192];
        const float4 vn = *reinterpret_cast<const float4*>(vnode + (size_t)b * H + c4);
        s0.x += s1.x + s2.x + s3.x + vn.x;
        s0.y += s1.y + s2.y + s3.y + vn.y;
        s0.z += s1.z + s2.z + s3.z + vn.z;
        s0.w += s1.w + s2.w + s3.w + vn.w;
        *reinterpret_cast<float4*>(h0 + (size_t)b * H + c4) = s0;
    }
}

// K2: h1 = h0 @ W1 + b1 ([1024,256]x[256,256]); 4 rows per block, W1 streamed
// coalesced (L2-resident, 256KB). Also accumulates BN column sum / sumsq.
__global__ void __launch_bounds__(256) gemm1_k(const float* __restrict__ h0,
                                               const float* __restrict__ W1,
                                               const float* __restrict__ b1,
                                               float* __restrict__ h1,
                                               float* __restrict__ colsum,
                                               float* __restrict__ colsumsq) {
    __shared__ float a[4][H];
    const int t = threadIdx.x;
    const int r0 = blockIdx.x << 2;
#pragma unroll
    for (int i = 0; i < 4; ++i) a[i][t] = h0[(size_t)(r0 + i) * H + t];
    __syncthreads();

    const float bb = b1[t];
    float acc0 = bb, acc1 = bb, acc2 = bb, acc3 = bb;
#pragma unroll 8
    for (int k = 0; k < H; ++k) {
        const float w = W1[(size_t)k * H + t];   // coalesced across t, broadcast a[][k]
        acc0 = fmaf(a[0][k], w, acc0);
        acc1 = fmaf(a[1][k], w, acc1);
        acc2 = fmaf(a[2][k], w, acc2);
        acc3 = fmaf(a[3][k], w, acc3);
    }
    h1[(size_t)(r0 + 0) * H + t] = acc0;
    h1[(size_t)(r0 + 1) * H + t] = acc1;
    h1[(size_t)(r0 + 2) * H + t] = acc2;
    h1[(size_t)(r0 + 3) * H + t] = acc3;

    const float s  = acc0 + acc1 + acc2 + acc3;
    const float sq = acc0 * acc0 + acc1 * acc1 + acc2 * acc2 + acc3 * acc3;
    atomicAdd(&colsum[t], s);
    atomicAdd(&colsumsq[t], sq);
}

// K3: vn = relu(BN(h1)) @ W2 + b2. BN applied on the fly from colsum/colsumsq.
// vn written directly to d_out's second output slot.
__global__ void __launch_bounds__(256) gemm2_k(const float* __restrict__ h1,
                                               const float* __restrict__ colsum,
                                               const float* __restrict__ colsumsq,
                                               const float* __restrict__ gamma,
                                               const float* __restrict__ beta,
                                               const float* __restrict__ W2,
                                               const float* __restrict__ b2,
                                               float* __restrict__ out_vn) {
    __shared__ float a[4][H];
    const int t = threadIdx.x;
    const int r0 = blockIdx.x << 2;

    const float invB = 1.0f / (float)Bg;
    const float m   = colsum[t] * invB;
    const float var = colsumsq[t] * invB - m * m;
    const float g   = gamma[t] * rsqrtf(var + EPSV);
    const float be  = beta[t];

#pragma unroll
    for (int i = 0; i < 4; ++i) {
        float v = h1[(size_t)(r0 + i) * H + t];
        v = (v - m) * g + be;
        a[i][t] = fmaxf(v, 0.0f);
    }
    __syncthreads();

    const float bb = b2[t];
    float acc0 = bb, acc1 = bb, acc2 = bb, acc3 = bb;
#pragma unroll 8
    for (int k = 0; k < H; ++k) {
        const float w = W2[(size_t)k * H + t];
        acc0 = fmaf(a[0][k], w, acc0);
        acc1 = fmaf(a[1][k], w, acc1);
        acc2 = fmaf(a[2][k], w, acc2);
        acc3 = fmaf(a[3][k], w, acc3);
    }
    out_vn[(size_t)(r0 + 0) * H + t] = acc0;
    out_vn[(size_t)(r0 + 1) * H + t] = acc1;
    out_vn[(size_t)(r0 + 2) * H + t] = acc2;
    out_vn[(size_t)(r0 + 3) * H + t] = acc3;
}

// K4: x_out = x + vn[batch_idx]. Contiguous row chunks per block, float4.
// vn is 1 MB -> L2/L3-resident gather; bidx read is wave-uniform per row.
__global__ void __launch_bounds__(256) gather_add_k(const float* __restrict__ x,
                                                    const int* __restrict__ bidx,
                                                    const float* __restrict__ vn,
                                                    float* __restrict__ xout,
                                                    int N, int rpb) {
    const int t = threadIdx.x;
    const int r0 = blockIdx.x * rpb;
    const int r1 = min(N, r0 + rpb);
    const int sub = t >> 6;
    const int c4  = (t & 63) << 2;

    for (int r = r0 + sub; r < r1; r += 4) {
        const int b = bidx[r];
        float4 xv = *reinterpret_cast<const float4*>(x + (size_t)r * H + c4);
        const float4 vv = *reinterpret_cast<const float4*>(vn + (size_t)b * H + c4);
        xv.x += vv.x; xv.y += vv.y; xv.z += vv.z; xv.w += vv.w;
        *reinterpret_cast<float4*>(xout + (size_t)r * H + c4) = xv;
    }
}

extern "C" void kernel_launch(void* const* d_in, const int* in_sizes, int n_in,
                              void* d_out, int out_size, void* d_ws, size_t ws_size,
                              hipStream_t stream) {
    const float* x     = (const float*)d_in[0];
    const int*   bidx  = (const int*)d_in[1];
    const float* vnode = (const float*)d_in[2];
    const float* W1    = (const float*)d_in[3];
    const float* b1    = (const float*)d_in[4];
    const float* gamma = (const float*)d_in[5];
    const float* beta  = (const float*)d_in[6];
    const float* W2    = (const float*)d_in[7];
    const float* b2    = (const float*)d_in[8];

    const int N = in_sizes[1];            // 500000

    float* out_x  = (float*)d_out;
    float* out_vn = out_x + (size_t)N * H;

    float* ws       = (float*)d_ws;
    float* h0       = ws;                  // B*H
    float* h1       = ws + (size_t)Bg * H; // B*H
    float* colsum   = ws + (size_t)2 * Bg * H;  // H
    float* colsumsq = colsum + H;               // H

    seg_sum_k<<<Bg, 256, 0, stream>>>(x, bidx, vnode, h0, colsum, colsumsq, N);
    gemm1_k<<<Bg / 4, 256, 0, stream>>>(h0, W1, b1, h1, colsum, colsumsq);
    gemm2_k<<<Bg / 4, 256, 0, stream>>>(h1, colsum, colsumsq, gamma, beta, W2, b2, out_vn);

    const int blocks = 2048;
    const int rpb = ((N + blocks - 1) / blocks + 3) & ~3;
    gather_add_k<<<blocks, 256, 0, stream>>>(x, bidx, out_vn, out_x, N, rpb);
}